// Round 1
// baseline (1224.766 us; speedup 1.0000x reference)
//
#include <hip/hip_runtime.h>

#define NROWS 65536
#define KCODES 1024
#define DDIM 256

// output offsets in floats (concat of reference return tuple)
#define Q_OFF    0
#define LOSS_OFF 16777216
#define PERP_OFF 16777217
#define IND_OFF  16777218
#define DIST_OFF 16842754

typedef unsigned long long u64;

// ---------------- init workspace (no hipMemset inside capture, use a kernel) ----
__global__ __launch_bounds__(256) void init_kernel(u64* __restrict__ keys,
                                                   unsigned int* __restrict__ hist,
                                                   double* __restrict__ loss) {
    int i = blockIdx.x * 256 + threadIdx.x;
    if (i < NROWS) keys[i] = ~0ull;
    if (i < KCODES) hist[i] = 0u;
    if (i == 0) *loss = 0.0;
}

// ---------------- squared norms of latent rows and embedding rows --------------
__global__ __launch_bounds__(256) void sqnorm_kernel(
    const float* __restrict__ lat, const float* __restrict__ emb,
    float* __restrict__ row_sq, float* __restrict__ emb_sq) {
    int gwave = (blockIdx.x * 256 + threadIdx.x) >> 6;
    int lane = threadIdx.x & 63;
    if (gwave >= NROWS + KCODES) return;
    const float* src = (gwave < NROWS) ? lat + (size_t)gwave * DDIM
                                       : emb + (size_t)(gwave - NROWS) * DDIM;
    float4 v = *reinterpret_cast<const float4*>(src + lane * 4);
    float s = v.x * v.x + v.y * v.y + v.z * v.z + v.w * v.w;
#pragma unroll
    for (int m = 32; m >= 1; m >>= 1) s += __shfl_xor(s, m, 64);
    if (lane == 0) {
        if (gwave < NROWS) row_sq[gwave] = s;
        else emb_sq[gwave - NROWS] = s;
    }
}

// ---------------- dist GEMM: 128x128 tile, BK=16, 8x8 micro-tile ---------------
__global__ __launch_bounds__(256) void dist_kernel(
    const float* __restrict__ A, const float* __restrict__ B,
    const float* __restrict__ row_sq, const float* __restrict__ emb_sq,
    float* __restrict__ dist, u64* __restrict__ keys) {
    __shared__ float As[16][132];  // transposed A chunk, pad 132 to break conflicts
    __shared__ float Bs[16][132];  // transposed B chunk
    const int tid = threadIdx.x;
    const int tx = tid & 15, ty = tid >> 4;
    const int row0 = blockIdx.y * 128, col0 = blockIdx.x * 128;

    float acc[8][8];
#pragma unroll
    for (int i = 0; i < 8; ++i)
#pragma unroll
        for (int j = 0; j < 8; ++j) acc[i][j] = 0.0f;

    for (int d0 = 0; d0 < DDIM; d0 += 16) {
#pragma unroll
        for (int i = 0; i < 2; ++i) {
            int l = tid + i * 256;            // 0..511 -> 128 rows x 4 float4
            int r = l >> 2, c4 = l & 3;
            float4 va = *reinterpret_cast<const float4*>(
                A + (size_t)(row0 + r) * DDIM + d0 + c4 * 4);
            As[c4 * 4 + 0][r] = va.x;
            As[c4 * 4 + 1][r] = va.y;
            As[c4 * 4 + 2][r] = va.z;
            As[c4 * 4 + 3][r] = va.w;
            float4 vb = *reinterpret_cast<const float4*>(
                B + (size_t)(col0 + r) * DDIM + d0 + c4 * 4);
            Bs[c4 * 4 + 0][r] = vb.x;
            Bs[c4 * 4 + 1][r] = vb.y;
            Bs[c4 * 4 + 2][r] = vb.z;
            Bs[c4 * 4 + 3][r] = vb.w;
        }
        __syncthreads();
#pragma unroll
        for (int d = 0; d < 16; ++d) {
            float4 a0 = *reinterpret_cast<const float4*>(&As[d][ty * 4]);
            float4 a1 = *reinterpret_cast<const float4*>(&As[d][64 + ty * 4]);
            float4 b0 = *reinterpret_cast<const float4*>(&Bs[d][tx * 4]);
            float4 b1 = *reinterpret_cast<const float4*>(&Bs[d][64 + tx * 4]);
            float a[8] = {a0.x, a0.y, a0.z, a0.w, a1.x, a1.y, a1.z, a1.w};
            float b[8] = {b0.x, b0.y, b0.z, b0.w, b1.x, b1.y, b1.z, b1.w};
#pragma unroll
            for (int i = 0; i < 8; ++i)
#pragma unroll
                for (int j = 0; j < 8; ++j) acc[i][j] += a[i] * b[j];
        }
        __syncthreads();
    }

    // epilogue: dist = ||x||^2 + ||e||^2 - 2*dot ; write + per-row argmin
    int gcols[8];
    float es[8];
#pragma unroll
    for (int j = 0; j < 8; ++j) {
        gcols[j] = col0 + ((j < 4) ? tx * 4 + j : 64 + tx * 4 + (j - 4));
        es[j] = emb_sq[gcols[j]];
    }
#pragma unroll
    for (int i = 0; i < 8; ++i) {
        int grow = row0 + ((i < 4) ? ty * 4 + i : 64 + ty * 4 + (i - 4));
        float rs = row_sq[grow];
        float dv[8];
#pragma unroll
        for (int j = 0; j < 8; ++j) dv[j] = (rs + es[j]) - 2.0f * acc[i][j];
        float4 w0 = make_float4(dv[0], dv[1], dv[2], dv[3]);
        float4 w1 = make_float4(dv[4], dv[5], dv[6], dv[7]);
        *reinterpret_cast<float4*>(dist + (size_t)grow * KCODES + col0 + tx * 4) = w0;
        *reinterpret_cast<float4*>(dist + (size_t)grow * KCODES + col0 + 64 + tx * 4) = w1;
        // local argmin (cols ascending -> first-occurrence semantics)
        float bv = dv[0];
        int bc = gcols[0];
#pragma unroll
        for (int j = 1; j < 8; ++j) {
            if (dv[j] < bv || (dv[j] == bv && gcols[j] < bc)) { bv = dv[j]; bc = gcols[j]; }
        }
        // reduce across the 16 lanes sharing this ty (xor masks flip tx bits only)
#pragma unroll
        for (int m = 8; m >= 1; m >>= 1) {
            float ov = __shfl_xor(bv, m, 64);
            int oc = __shfl_xor(bc, m, 64);
            if (ov < bv || (ov == bv && oc < bc)) { bv = ov; bc = oc; }
        }
        if (tx == 0) {
            u64 key = ((u64)__float_as_uint(bv) << 32) | (unsigned)bc;
            atomicMin(&keys[grow], key);
        }
    }
}

// ---------------- per-row gather, quantized_st, loss accum, histogram ----------
__global__ __launch_bounds__(64) void gather_kernel(
    const float* __restrict__ lat, const float* __restrict__ emb,
    const u64* __restrict__ keys, float* __restrict__ qout,
    float* __restrict__ indout, unsigned int* __restrict__ hist,
    double* __restrict__ loss) {
    int row = blockIdx.x;
    int lane = threadIdx.x;
    int idx = (int)(unsigned)(keys[row] & 0xFFFFFFFFull);
    float4 ev = *reinterpret_cast<const float4*>(emb + (size_t)idx * DDIM + lane * 4);
    float4 xv = *reinterpret_cast<const float4*>(lat + (size_t)row * DDIM + lane * 4);
    float dx = ev.x - xv.x, dy = ev.y - xv.y, dz = ev.z - xv.z, dw = ev.w - xv.w;
    // straight-through: x + (q - x), matching ref rounding
    float4 q = make_float4(xv.x + dx, xv.y + dy, xv.z + dz, xv.w + dw);
    *reinterpret_cast<float4*>(qout + (size_t)row * DDIM + lane * 4) = q;
    float s = dx * dx + dy * dy + dz * dz + dw * dw;
#pragma unroll
    for (int m = 32; m >= 1; m >>= 1) s += __shfl_xor(s, m, 64);
    if (lane == 0) {
        atomicAdd(loss, (double)s);
        atomicAdd(&hist[idx], 1u);
        indout[row] = (float)idx;
    }
}

// ---------------- scalars: vq_loss, perplexity --------------------------------
__global__ __launch_bounds__(1024) void scalar_kernel(
    const unsigned int* __restrict__ hist, const double* __restrict__ loss,
    float* __restrict__ out_loss, float* __restrict__ out_perp) {
    __shared__ float red[16];
    int t = threadIdx.x;
    float p = (float)hist[t] / 65536.0f;
    float s = p * logf(p + 1e-10f);
#pragma unroll
    for (int m = 32; m >= 1; m >>= 1) s += __shfl_xor(s, m, 64);
    if ((t & 63) == 0) red[t >> 6] = s;
    __syncthreads();
    if (t < 64) {
        float v = (t < 16) ? red[t] : 0.0f;
#pragma unroll
        for (int m = 32; m >= 1; m >>= 1) v += __shfl_xor(v, m, 64);
        if (t == 0) {
            *out_perp = expf(-v);
            double ml = *loss / (double)((size_t)NROWS * DDIM);
            *out_loss = (float)(ml * 0.25 + ml);  // beta*commit + delta*embed (equal)
        }
    }
}

extern "C" void kernel_launch(void* const* d_in, const int* in_sizes, int n_in,
                              void* d_out, int out_size, void* d_ws, size_t ws_size,
                              hipStream_t stream) {
    const float* lat = (const float*)d_in[0];
    const float* emb = (const float*)d_in[1];
    float* out = (float*)d_out;
    char* ws = (char*)d_ws;

    u64* keys = (u64*)ws;                               // 65536*8   = 524288 B
    float* row_sq = (float*)(ws + 524288);              // 65536*4   = 262144 B
    float* emb_sq = (float*)(ws + 786432);              // 1024*4    = 4096 B
    unsigned int* hist = (unsigned int*)(ws + 790528);  // 1024*4    = 4096 B
    double* loss = (double*)(ws + 794624);              // 8 B

    init_kernel<<<256, 256, 0, stream>>>(keys, hist, loss);
    sqnorm_kernel<<<(NROWS + KCODES) / 4, 256, 0, stream>>>(lat, emb, row_sq, emb_sq);
    dim3 grid(KCODES / 128, NROWS / 128);
    dist_kernel<<<grid, 256, 0, stream>>>(lat, emb, row_sq, emb_sq,
                                          out + DIST_OFF, keys);
    gather_kernel<<<NROWS, 64, 0, stream>>>(lat, emb, keys, out + Q_OFF,
                                            out + IND_OFF, hist, loss);
    scalar_kernel<<<1, 1024, 0, stream>>>(hist, loss, out + LOSS_OFF, out + PERP_OFF);
}

// Round 2
// 467.015 us; speedup vs baseline: 2.6225x; 2.6225x over previous
//
#include <hip/hip_runtime.h>

#define NROWS 65536
#define KCODES 1024
#define DDIM 256

// output offsets in floats (concat of reference return tuple)
#define Q_OFF    0
#define LOSS_OFF 16777216
#define PERP_OFF 16777217
#define IND_OFF  16777218
#define DIST_OFF 16842754

#define GATHER_BLOCKS (NROWS / 4)   // 16384 partial-loss slots

typedef unsigned long long u64;

// ---------------- init workspace (no hipMemset inside capture, use a kernel) ----
__global__ __launch_bounds__(256) void init_kernel(u64* __restrict__ keys,
                                                   unsigned int* __restrict__ hist) {
    int i = blockIdx.x * 256 + threadIdx.x;
    if (i < NROWS) keys[i] = ~0ull;
    if (i < KCODES) hist[i] = 0u;
}

// ---------------- squared norms of latent rows and embedding rows --------------
__global__ __launch_bounds__(256) void sqnorm_kernel(
    const float* __restrict__ lat, const float* __restrict__ emb,
    float* __restrict__ row_sq, float* __restrict__ emb_sq) {
    int gwave = (blockIdx.x * 256 + threadIdx.x) >> 6;
    int lane = threadIdx.x & 63;
    if (gwave >= NROWS + KCODES) return;
    const float* src = (gwave < NROWS) ? lat + (size_t)gwave * DDIM
                                       : emb + (size_t)(gwave - NROWS) * DDIM;
    float4 v = *reinterpret_cast<const float4*>(src + lane * 4);
    float s = v.x * v.x + v.y * v.y + v.z * v.z + v.w * v.w;
#pragma unroll
    for (int m = 32; m >= 1; m >>= 1) s += __shfl_xor(s, m, 64);
    if (lane == 0) {
        if (gwave < NROWS) row_sq[gwave] = s;
        else emb_sq[gwave - NROWS] = s;
    }
}

// ---------------- dist GEMM: 128x128 tile, BK=16, 8x8 micro-tile ---------------
__global__ __launch_bounds__(256) void dist_kernel(
    const float* __restrict__ A, const float* __restrict__ B,
    const float* __restrict__ row_sq, const float* __restrict__ emb_sq,
    float* __restrict__ dist, u64* __restrict__ keys) {
    __shared__ float As[16][132];  // transposed A chunk, pad 132 to break conflicts
    __shared__ float Bs[16][132];  // transposed B chunk
    const int tid = threadIdx.x;
    const int tx = tid & 15, ty = tid >> 4;
    const int row0 = blockIdx.y * 128, col0 = blockIdx.x * 128;

    float acc[8][8];
#pragma unroll
    for (int i = 0; i < 8; ++i)
#pragma unroll
        for (int j = 0; j < 8; ++j) acc[i][j] = 0.0f;

    for (int d0 = 0; d0 < DDIM; d0 += 16) {
#pragma unroll
        for (int i = 0; i < 2; ++i) {
            int l = tid + i * 256;            // 0..511 -> 128 rows x 4 float4
            int r = l >> 2, c4 = l & 3;
            float4 va = *reinterpret_cast<const float4*>(
                A + (size_t)(row0 + r) * DDIM + d0 + c4 * 4);
            As[c4 * 4 + 0][r] = va.x;
            As[c4 * 4 + 1][r] = va.y;
            As[c4 * 4 + 2][r] = va.z;
            As[c4 * 4 + 3][r] = va.w;
            float4 vb = *reinterpret_cast<const float4*>(
                B + (size_t)(col0 + r) * DDIM + d0 + c4 * 4);
            Bs[c4 * 4 + 0][r] = vb.x;
            Bs[c4 * 4 + 1][r] = vb.y;
            Bs[c4 * 4 + 2][r] = vb.z;
            Bs[c4 * 4 + 3][r] = vb.w;
        }
        __syncthreads();
#pragma unroll
        for (int d = 0; d < 16; ++d) {
            float4 a0 = *reinterpret_cast<const float4*>(&As[d][ty * 4]);
            float4 a1 = *reinterpret_cast<const float4*>(&As[d][64 + ty * 4]);
            float4 b0 = *reinterpret_cast<const float4*>(&Bs[d][tx * 4]);
            float4 b1 = *reinterpret_cast<const float4*>(&Bs[d][64 + tx * 4]);
            float a[8] = {a0.x, a0.y, a0.z, a0.w, a1.x, a1.y, a1.z, a1.w};
            float b[8] = {b0.x, b0.y, b0.z, b0.w, b1.x, b1.y, b1.z, b1.w};
#pragma unroll
            for (int i = 0; i < 8; ++i)
#pragma unroll
                for (int j = 0; j < 8; ++j) acc[i][j] += a[i] * b[j];
        }
        __syncthreads();
    }

    // epilogue: dist = ||x||^2 + ||e||^2 - 2*dot ; write + per-row argmin
    int gcols[8];
    float es[8];
#pragma unroll
    for (int j = 0; j < 8; ++j) {
        gcols[j] = col0 + ((j < 4) ? tx * 4 + j : 64 + tx * 4 + (j - 4));
        es[j] = emb_sq[gcols[j]];
    }
#pragma unroll
    for (int i = 0; i < 8; ++i) {
        int grow = row0 + ((i < 4) ? ty * 4 + i : 64 + ty * 4 + (i - 4));
        float rs = row_sq[grow];
        float dv[8];
#pragma unroll
        for (int j = 0; j < 8; ++j) dv[j] = (rs + es[j]) - 2.0f * acc[i][j];
        float4 w0 = make_float4(dv[0], dv[1], dv[2], dv[3]);
        float4 w1 = make_float4(dv[4], dv[5], dv[6], dv[7]);
        *reinterpret_cast<float4*>(dist + (size_t)grow * KCODES + col0 + tx * 4) = w0;
        *reinterpret_cast<float4*>(dist + (size_t)grow * KCODES + col0 + 64 + tx * 4) = w1;
        // local argmin (cols ascending -> first-occurrence semantics)
        float bv = dv[0];
        int bc = gcols[0];
#pragma unroll
        for (int j = 1; j < 8; ++j) {
            if (dv[j] < bv || (dv[j] == bv && gcols[j] < bc)) { bv = dv[j]; bc = gcols[j]; }
        }
        // reduce across the 16 lanes sharing this ty (xor masks flip tx bits only)
#pragma unroll
        for (int m = 8; m >= 1; m >>= 1) {
            float ov = __shfl_xor(bv, m, 64);
            int oc = __shfl_xor(bc, m, 64);
            if (ov < bv || (ov == bv && oc < bc)) { bv = ov; bc = oc; }
        }
        if (tx == 0) {
            u64 key = ((u64)__float_as_uint(bv) << 32) | (unsigned)bc;
            atomicMin(&keys[grow], key);
        }
    }
}

// ---- per-row gather, quantized_st, histogram; per-block (4-row) loss partial ---
__global__ __launch_bounds__(256) void gather_kernel(
    const float* __restrict__ lat, const float* __restrict__ emb,
    const u64* __restrict__ keys, float* __restrict__ qout,
    float* __restrict__ indout, unsigned int* __restrict__ hist,
    float* __restrict__ loss_part) {
    __shared__ float lred[4];
    const int wave = threadIdx.x >> 6;
    const int lane = threadIdx.x & 63;
    const int row = blockIdx.x * 4 + wave;
    int idx = (int)(unsigned)(keys[row] & 0xFFFFFFFFull);
    float4 ev = *reinterpret_cast<const float4*>(emb + (size_t)idx * DDIM + lane * 4);
    float4 xv = *reinterpret_cast<const float4*>(lat + (size_t)row * DDIM + lane * 4);
    float dx = ev.x - xv.x, dy = ev.y - xv.y, dz = ev.z - xv.z, dw = ev.w - xv.w;
    // straight-through: x + (q - x), matching ref rounding
    float4 q = make_float4(xv.x + dx, xv.y + dy, xv.z + dz, xv.w + dw);
    *reinterpret_cast<float4*>(qout + (size_t)row * DDIM + lane * 4) = q;
    float s = dx * dx + dy * dy + dz * dz + dw * dw;
#pragma unroll
    for (int m = 32; m >= 1; m >>= 1) s += __shfl_xor(s, m, 64);
    if (lane == 0) {
        lred[wave] = s;
        atomicAdd(&hist[idx], 1u);
        indout[row] = (float)idx;
    }
    __syncthreads();
    if (threadIdx.x == 0)
        loss_part[blockIdx.x] = (lred[0] + lred[1]) + (lred[2] + lred[3]);
}

// ---------------- scalars: vq_loss (reduce partials), perplexity ---------------
__global__ __launch_bounds__(1024) void scalar_kernel(
    const unsigned int* __restrict__ hist, const float* __restrict__ loss_part,
    float* __restrict__ out_loss, float* __restrict__ out_perp) {
    __shared__ double lred[16];
    __shared__ float ered[16];
    int t = threadIdx.x;
    double ls = 0.0;
#pragma unroll
    for (int i = 0; i < GATHER_BLOCKS / 1024; ++i)
        ls += (double)loss_part[t + i * 1024];
    float p = (float)hist[t] / 65536.0f;
    float es = p * logf(p + 1e-10f);
#pragma unroll
    for (int m = 32; m >= 1; m >>= 1) {
        ls += __shfl_xor(ls, m, 64);
        es += __shfl_xor(es, m, 64);
    }
    if ((t & 63) == 0) { lred[t >> 6] = ls; ered[t >> 6] = es; }
    __syncthreads();
    if (t < 64) {
        double lv = (t < 16) ? lred[t] : 0.0;
        float ev = (t < 16) ? ered[t] : 0.0f;
#pragma unroll
        for (int m = 32; m >= 1; m >>= 1) {
            lv += __shfl_xor(lv, m, 64);
            ev += __shfl_xor(ev, m, 64);
        }
        if (t == 0) {
            *out_perp = expf(-ev);
            double ml = lv / (double)((size_t)NROWS * DDIM);
            *out_loss = (float)(ml * 0.25 + ml);  // beta*commit + delta*embed (equal)
        }
    }
}

extern "C" void kernel_launch(void* const* d_in, const int* in_sizes, int n_in,
                              void* d_out, int out_size, void* d_ws, size_t ws_size,
                              hipStream_t stream) {
    const float* lat = (const float*)d_in[0];
    const float* emb = (const float*)d_in[1];
    float* out = (float*)d_out;
    char* ws = (char*)d_ws;

    u64* keys = (u64*)ws;                               // 65536*8   = 524288 B
    float* row_sq = (float*)(ws + 524288);              // 65536*4   = 262144 B
    float* emb_sq = (float*)(ws + 786432);              // 1024*4    = 4096 B
    unsigned int* hist = (unsigned int*)(ws + 790528);  // 1024*4    = 4096 B
    float* loss_part = (float*)(ws + 794624);           // 16384*4   = 65536 B

    init_kernel<<<256, 256, 0, stream>>>(keys, hist);
    sqnorm_kernel<<<(NROWS + KCODES) / 4, 256, 0, stream>>>(lat, emb, row_sq, emb_sq);
    dim3 grid(KCODES / 128, NROWS / 128);
    dist_kernel<<<grid, 256, 0, stream>>>(lat, emb, row_sq, emb_sq,
                                          out + DIST_OFF, keys);
    gather_kernel<<<GATHER_BLOCKS, 256, 0, stream>>>(lat, emb, keys, out + Q_OFF,
                                                     out + IND_OFF, hist, loss_part);
    scalar_kernel<<<1, 1024, 0, stream>>>(hist, loss_part,
                                          out + LOSS_OFF, out + PERP_OFF);
}